// Round 16
// baseline (317.993 us; speedup 1.0000x reference)
//
#include <hip/hip_runtime.h>
#include <cstddef>

#define G_    128
#define NPG_  256
#define EPG_  4096
#define NN_   32768
#define EE_   524288
#define KK_   2048
#define GK_   262144

// d_out layout (floats): [score E][causal_w GK][conf_w GK][causal_ei 2*GK][conf_ei 2*GK][cmask N][dmask N]
#define O_CW  524288
#define O_DW  786432
#define O_CEI 1048576
#define O_FEI 1572864
#define O_CM  2097152
#define O_DM  2129920

typedef float v4f __attribute__((ext_vector_type(4)));
typedef unsigned long long u64;

struct BiasCfg {
  const float* b[8];
};

__device__ __forceinline__ void cswap(u64& a, u64& b, bool d) {
  u64 hi = a > b ? a : b, lo = a > b ? b : a;
  a = d ? hi : lo;
  b = d ? lo : hi;
}

// ---------------- GEMM body v19 (gemm#1/#2): GLOBAL-W 4x4, nt stores, N-split (proven best:
// R9-ledger showed W-in-LDS at ncb=1 has zero amortization, +10us/launch). nt-envelope rule:
// <=1 outstanding nt stream per block — __syncthreads() AFTER each cb's store burst. ----------------
__device__ __forceinline__ void gemm_wt_body(const float* __restrict__ in, int istride,
                                             const float* __restrict__ WT, int wstride,
                                             const BiasCfg& bc, int cb0, int ncb,
                                             float* __restrict__ out, int ostride,
                                             int bx, float* xT) {
  const int tid = threadIdx.x;
  const int r0 = bx * 64;
#pragma unroll
  for (int it = 0; it < 16; ++it) {
    int idx = tid + it * 256;
    int rr = idx >> 6, kk = idx & 63;
    xT[kk * 68 + rr] = in[(r0 + rr) * istride + kk];
  }
  __syncthreads();
  const int c4 = (tid & 15) * 4;
  const int r4 = (tid >> 4) * 4;
  for (int cb = cb0; cb < cb0 + ncb; ++cb) {
    const float* wp = WT + cb * 64 + c4;
    const float* bp = bc.b[cb];
    float acc[4][4] = {};
#pragma unroll
    for (int k = 0; k < 64; ++k) {
      float4 xv = *(const float4*)&xT[k * 68 + r4];
      float4 wv = *(const float4*)&wp[(size_t)k * wstride];
      float xr[4] = {xv.x, xv.y, xv.z, xv.w};
      float wc[4] = {wv.x, wv.y, wv.z, wv.w};
#pragma unroll
      for (int a = 0; a < 4; ++a)
#pragma unroll
        for (int b = 0; b < 4; ++b)
          acc[a][b] = fmaf(xr[a], wc[b], acc[a][b]);
    }
    float bx4[4] = {0.f, 0.f, 0.f, 0.f};
    if (bp) {
      float4 bb = *(const float4*)&bp[c4];
      bx4[0] = bb.x; bx4[1] = bb.y; bx4[2] = bb.z; bx4[3] = bb.w;
    }
#pragma unroll
    for (int ri = 0; ri < 4; ++ri) {
      v4f st;
      st.x = acc[ri][0] + bx4[0];
      st.y = acc[ri][1] + bx4[1];
      st.z = acc[ri][2] + bx4[2];
      st.w = acc[ri][3] + bx4[3];
      __builtin_nontemporal_store(st, (v4f*)&out[(r0 + r4 + ri) * ostride + cb * 64 + c4]);
    }
    __syncthreads();  // drain nt burst — the nt-envelope invariant
  }
}

__global__ __launch_bounds__(256, 4) void gemm_wt(const float* __restrict__ in, int istride,
                                                  const float* __restrict__ WT, int wstride,
                                                  BiasCfg bc, int ncb_per,
                                                  float* __restrict__ out, int ostride) {
  __shared__ float xT[64 * 68];
  gemm_wt_body(in, istride, WT, wstride, bc, blockIdx.y * ncb_per, ncb_per,
               out, ostride, blockIdx.x, xT);
}

// ---------------- gemm_wt8 (proven, for gemm#3): 128x128 (cb pair) tile, 8x8/thread,
// W staged in LDS, nt stores. Probed 5 ways (occupancy/reg-pipeline/W-source/blocking/
// store-path) — all null; closed at ~42us (latency-bound at 2 waves/SIMD, 68.6KB LDS). ----------------
__global__ __launch_bounds__(256, 2) void gemm_wt8(const float* __restrict__ in, int istride,
                                                   const float* __restrict__ WT, int wstride,
                                                   BiasCfg bc, int cbs_per_y,
                                                   float* __restrict__ out, int ostride) {
  __shared__ float xT[64 * 132];   // [k][row 0..127], pad 4
  __shared__ float wS[64 * 136];   // [k][pair: cb0 cols @0, cb1 cols @68]
  const int tid = threadIdx.x;
  const int r0 = blockIdx.x * 128;
  const int cbbase = blockIdx.y * cbs_per_y;
#pragma unroll
  for (int it = 0; it < 32; ++it) {
    int idx = tid + it * 256;            // 0..8191: 128 rows x 64 k
    int rr = idx >> 6, kk = idx & 63;
    xT[kk * 132 + rr] = in[(size_t)(r0 + rr) * istride + kk];
  }
  const int c4 = (tid & 15) * 4;
  const int r8 = (tid >> 4) * 8;
  for (int pr = 0; pr < cbs_per_y; pr += 2) {
    const int cb0 = cbbase + pr;
#pragma unroll
    for (int it = 0; it < 8; ++it) {     // stage both panels of the pair
      int idx = tid + it * 256;          // 0..2047 float4 slots
      int p = idx >> 10, rem = idx & 1023;
      int k = rem >> 4, c16 = (rem & 15) * 4;
      *(float4*)&wS[k * 136 + p * 68 + c16] =
          *(const float4*)&WT[(size_t)k * wstride + (cb0 + p) * 64 + c16];
    }
    __syncthreads();                     // wS (and on first pair: xT) ready
    float acc0[8][4] = {};
    float acc1[8][4] = {};
#pragma unroll 4
    for (int k = 0; k < 64; ++k) {
      float4 xlo = *(const float4*)&xT[k * 132 + r8];
      float4 xhi = *(const float4*)&xT[k * 132 + r8 + 4];
      float4 w0 = *(const float4*)&wS[k * 136 + c4];
      float4 w1 = *(const float4*)&wS[k * 136 + 68 + c4];
      float xr[8] = {xlo.x, xlo.y, xlo.z, xlo.w, xhi.x, xhi.y, xhi.z, xhi.w};
      float wc0[4] = {w0.x, w0.y, w0.z, w0.w};
      float wc1[4] = {w1.x, w1.y, w1.z, w1.w};
#pragma unroll
      for (int a = 0; a < 8; ++a) {
#pragma unroll
        for (int b = 0; b < 4; ++b) {
          acc0[a][b] = fmaf(xr[a], wc0[b], acc0[a][b]);
          acc1[a][b] = fmaf(xr[a], wc1[b], acc1[a][b]);
        }
      }
    }
    {
      const float* bp = bc.b[cb0];
      float b4[4] = {0.f, 0.f, 0.f, 0.f};
      if (bp) {
        float4 bb = *(const float4*)&bp[c4];
        b4[0] = bb.x; b4[1] = bb.y; b4[2] = bb.z; b4[3] = bb.w;
      }
#pragma unroll
      for (int ri = 0; ri < 8; ++ri) {
        v4f st;
        st.x = acc0[ri][0] + b4[0];
        st.y = acc0[ri][1] + b4[1];
        st.z = acc0[ri][2] + b4[2];
        st.w = acc0[ri][3] + b4[3];
        __builtin_nontemporal_store(st, (v4f*)&out[(size_t)(r0 + r8 + ri) * ostride + cb0 * 64 + c4]);
      }
      __syncthreads();                   // drain cb0 nt burst
    }
    {
      const float* bp = bc.b[cb0 + 1];
      float b4[4] = {0.f, 0.f, 0.f, 0.f};
      if (bp) {
        float4 bb = *(const float4*)&bp[c4];
        b4[0] = bb.x; b4[1] = bb.y; b4[2] = bb.z; b4[3] = bb.w;
      }
#pragma unroll
      for (int ri = 0; ri < 8; ++ri) {
        v4f st;
        st.x = acc1[ri][0] + b4[0];
        st.y = acc1[ri][1] + b4[1];
        st.z = acc1[ri][2] + b4[2];
        st.w = acc1[ri][3] + b4[3];
        __builtin_nontemporal_store(st, (v4f*)&out[(size_t)(r0 + r8 + ri) * ostride + (cb0 + 1) * 64 + c4]);
      }
      __syncthreads();                   // drain cb1 nt burst; guards wS restage
    }
  }
}

// ---------------- prep: weight transposes (WmT/W1T/W2T) + zero masks ----------------
__global__ __launch_bounds__(256) void prep_kernel(const float* __restrict__ Wm1,
                                                   const float* __restrict__ W11, const float* __restrict__ W12,
                                                   const float* __restrict__ W13,
                                                   const float* __restrict__ W21, const float* __restrict__ W22,
                                                   const float* __restrict__ W23,
                                                   float* __restrict__ WmT, float* __restrict__ W1T,
                                                   float* __restrict__ W2T, int* __restrict__ masks) {
  const int b = blockIdx.x;
  const int tid = threadIdx.x;
  if (b < 64) {
    const int k = b;
#pragma unroll
    for (int t = 0; t < 2; ++t) {
      int j = t * 256 + tid;
      int row = j & 255;
      int koff = (j < 256) ? 0 : 64;
      WmT[k * 512 + j] = Wm1[row * 128 + koff + k];
    }
  } else if (b < 80) {
    const int kb = (b - 64) * 4;
    if (tid < 192) {
      int cb = tid >> 6, c = tid & 63;
      const float* Wsrc = (cb == 0) ? W11 : (cb == 1) ? W12 : W13;
#pragma unroll
      for (int s = 0; s < 4; ++s) {
        int k = kb + s;
        W1T[k * 192 + tid] = Wsrc[c * 64 + k];
      }
    }
  } else if (b < 96) {
    const int kb = (b - 80) * 4;
    if (tid < 192) {
      int cb = tid >> 6, c = tid & 63;
      const float* Wsrc = (cb == 0) ? W21 : (cb == 1) ? W22 : W23;
#pragma unroll
      for (int s = 0; s < 4; ++s) {
        int k = kb + s;
        W2T[k * 192 + tid] = Wsrc[c * 64 + k];
      }
    }
  } else {
    int idx = (b - 96) * 1024 + tid * 4;  // 64 blocks x 1024 ints = 65536 = 2*NN
    int4 z = {0, 0, 0, 0};
    *(int4*)&masks[idx] = z;
  }
}

// ---------------- build_dense: per-(group, col-half) LDS accumulation — no global atomics,
// no MT memset (every cell written), Wc = LDS column sums (no contention) ----------------
__global__ __launch_bounds__(256) void build_dense(const int* __restrict__ ei, const float* __restrict__ ea,
                                                   float* __restrict__ MT, float* __restrict__ Wc) {
  __shared__ float acc[NPG_ * 128];  // 128 KB: 256 rows x 128 cols (this block's column half)
  const int tid = threadIdx.x;
  const int g = blockIdx.x >> 1;
  const int c0 = (blockIdx.x & 1) * 128;
  const int gbase = g * NPG_;
  const size_t mbase = (size_t)g << 16;
  for (int i = tid * 4; i < NPG_ * 128; i += 1024) {
    float4 z = {0.f, 0.f, 0.f, 0.f};
    *(float4*)&acc[i] = z;
  }
  __syncthreads();
  const int ebase = g * EPG_;
#pragma unroll
  for (int it = 0; it < 16; ++it) {
    int e = ebase + it * 256 + tid;
    int r = ei[e] - gbase;
    int ch = ei[EE_ + e] - gbase - c0;
    float w = ea[e];
    if ((unsigned)ch < 128u) atomicAdd(&acc[r * 128 + ch], w);
  }
  __syncthreads();
  // write the half-slab: each row contributes 512 B aligned chunk
  for (int i = tid; i < NPG_ * 32; i += 256) {
    int r = i >> 5, c4 = (i & 31) * 4;
    *(float4*)&MT[mbase + (size_t)r * 256 + c0 + c4] = *(const float4*)&acc[r * 128 + c4];
  }
  // Wc column sums (lanes own columns; per-lane serial over r)
  if (tid < 128) {
    float s = 0.f;
    for (int r = 0; r < NPG_; ++r) s += acc[r * 128 + tid];
    Wc[gbase + c0 + tid] = s;
  }
}

// ---------------- mm_agg2 (v20): dense leconv aggregation, 128-node x 64-feat tiles,
// 8 nodes x 4 feats per thread. The 4x4 version was LDS-ISSUE-bound (2 b128 per 16 FMA ->
// 1.05e6 wave-reads ~= 20.5us floor per launch) and runs 16 waves/CU (latency well hidden,
// unlike gemm_wt8's blocking-null case) — so widening transfers: 3 b128 per 32 FMA (-25%
// reads/FMA). Row order (kc-major, r ascending) and per-output chains unchanged ->
// bitwise-identical. LDS 53.2KB -> 3 blocks/CU (12 waves). ----------------
__global__ __launch_bounds__(256) void mm_agg2(const float* __restrict__ MT, const float* __restrict__ buf,
                                               const float* __restrict__ Wc, float* __restrict__ hout,
                                               int do_relu) {
  __shared__ float Ms[64 * 136];   // [r][node 0..127], pad 8
  __shared__ float As[64 * 72];    // [r][feat 0..63], pad 8
  const int tid = threadIdx.x;
  const int g = blockIdx.x >> 1;
  const int c0 = (blockIdx.x & 1) * 128;
  const int gbase = g * NPG_;
  const size_t mbase = (size_t)g << 16;
  const int n8 = (tid >> 4) * 8;   // node offset within the 128-tile
  const int f4 = (tid & 15) * 4;   // feature (lane-contiguous)
  float acc[8][4] = {};
  for (int kc = 0; kc < 4; ++kc) {
#pragma unroll
    for (int it = 0; it < 8; ++it) {     // Ms: 64 r x 128 nodes = 2048 float4
      int idx = tid + it * 256;
      int rr = idx >> 5, c16 = (idx & 31) * 4;
      *(float4*)&Ms[rr * 136 + c16] = *(const float4*)&MT[mbase + (size_t)(kc * 64 + rr) * 256 + c0 + c16];
    }
#pragma unroll
    for (int it = 0; it < 4; ++it) {     // As: 64 r x 64 feats = 1024 float4
      int idx = tid + it * 256;
      int rr = idx >> 4, k16 = (idx & 15) * 4;
      *(float4*)&As[rr * 72 + k16] = *(const float4*)&buf[(gbase + kc * 64 + rr) * 192 + k16];
    }
    __syncthreads();
#pragma unroll
    for (int r = 0; r < 64; ++r) {
      float4 mlo = *(const float4*)&Ms[r * 136 + n8];
      float4 mhi = *(const float4*)&Ms[r * 136 + n8 + 4];
      float4 av = *(const float4*)&As[r * 72 + f4];
      float mr[8] = {mlo.x, mlo.y, mlo.z, mlo.w, mhi.x, mhi.y, mhi.z, mhi.w};
      float ak[4] = {av.x, av.y, av.z, av.w};
#pragma unroll
      for (int ci = 0; ci < 8; ++ci)
#pragma unroll
        for (int ki = 0; ki < 4; ++ki)
          acc[ci][ki] = fmaf(mr[ci], ak[ki], acc[ci][ki]);
    }
    __syncthreads();
  }
#pragma unroll
  for (int ci = 0; ci < 8; ++ci) {
    int n = gbase + c0 + n8 + ci;
    float wcn = Wc[n];
    float4 b4 = *(const float4*)&buf[n * 192 + 64 + f4];
    float4 cc4 = *(const float4*)&buf[n * 192 + 128 + f4];
    float4 st;
    st.x = acc[ci][0] - wcn * b4.x + cc4.x;
    st.y = acc[ci][1] - wcn * b4.y + cc4.y;
    st.z = acc[ci][2] - wcn * b4.z + cc4.z;
    st.w = acc[ci][3] - wcn * b4.w + cc4.w;
    if (do_relu) {
      st.x = fmaxf(st.x, 0.f); st.y = fmaxf(st.y, 0.f);
      st.z = fmaxf(st.z, 0.f); st.w = fmaxf(st.w, 0.f);
    }
    *(float4*)&hout[n * 64 + f4] = st;
  }
}

// ---------------- fused edge scores v16 (proven): v12 machinery + double-buffered t-slices,
// one barrier per t, T14 issue-early/write-late staging. Per-edge fp chain (t asc, k4 asc)
// matches v5..v12 -> scores bitwise-identical. ----------------
__global__ __launch_bounds__(512, 2) void score_v16(const float* __restrict__ pq, const int* __restrict__ ei,
                                                    const float* __restrict__ wm2, const float* __restrict__ bm2,
                                                    float* __restrict__ out) {
  __shared__ __align__(16) float S[20480];   // 80KB: buf0=[0,10240) buf1=[10240,20480); each = Ps[5120]+Qs[5120]
  int* ip = (int*)S;
  const int tid = threadIdx.x;
  const int g = blockIdx.x & 127;       // same-g blocks ≡ g (mod 8) -> same XCD, pq L2 reuse
  const int quarter = blockIdx.x >> 7;
  const int gbase = g * NPG_;
  const int ebase = g * EPG_ + quarter * 1024;
  // pad slot i (i in [0,2048)) -> float index (i>>2)*20 + 16 + (i&3)  (buffer-0 row pads)
  // slots: sorted[0,1024) hist[1024,1280) off[1280,1536) cur[1536,1792) wsum[1792,1796)
#define PADI(i) ((((i) >> 2) * 20) + 16 + ((i) & 3))
  if (tid < 256) { ip[PADI(1024 + tid)] = 0; ip[PADI(1536 + tid)] = 0; }
  int rr[2], cc[2];
#pragma unroll
  for (int j = 0; j < 2; ++j) {
    int e = ebase + j * 512 + tid;
    rr[j] = ei[e] - gbase;
    cc[j] = ei[EE_ + e] - gbase;
  }
  __syncthreads();
#pragma unroll
  for (int j = 0; j < 2; ++j) atomicAdd(&ip[PADI(1024 + rr[j])], 1);
  __syncthreads();
  int sv = 0, vv = 0;
  if (tid < 256) {                      // waves 0-3: 4x 64-lane inclusive scans
    const int l = tid & 63;
    vv = ip[PADI(1024 + tid)];
    sv = vv;
#pragma unroll
    for (int d = 1; d < 64; d <<= 1) {
      int u = __shfl_up(sv, d);
      if (l >= d) sv += u;
    }
    if (l == 63) ip[PADI(1792 + (tid >> 6))] = sv;
  }
  __syncthreads();
  if (tid < 256) {
    const int w = tid >> 6;
    int woff = 0;
#pragma unroll
    for (int ww = 0; ww < 3; ++ww)
      if (ww < w) woff += ip[PADI(1792 + ww)];
    ip[PADI(1280 + tid)] = woff + sv - vv;  // block-wide exclusive prefix (bucket start)
  }
  __syncthreads();
#pragma unroll
  for (int j = 0; j < 2; ++j) {
    int pos = ip[PADI(1280 + rr[j])] + atomicAdd(&ip[PADI(1536 + rr[j])], 1);
    ip[PADI(pos)] = (rr[j] << 19) | (cc[j] << 11) | (j * 512 + tid);
  }
  __syncthreads();
  int rl[2], cl[2], eo[2];
#pragma unroll
  for (int j = 0; j < 2; ++j) {          // consecutive lanes <- consecutive sorted ranks
    int rec = ip[PADI(j * 512 + tid)];
    rl[j] = (rec >> 19) * 20;
    cl[j] = ((rec >> 11) & 255) * 20;
    eo[j] = ebase + (rec & 2047);
  }
  // stage t=0 into buffer 0 (data lanes only; pads with sort records untouched, and the
  // records are already consumed into registers above)
  const int node0 = tid >> 2, k40 = (tid & 3) * 4;
  const int node1 = 128 + node0, k41 = k40;
  {
    const float* s0 = &pq[(size_t)(gbase + node0) * 512 + k40];
    const float* s1 = &pq[(size_t)(gbase + node1) * 512 + k41];
    *(float4*)&S[node0 * 20 + k40] = *(const float4*)s0;
    *(float4*)&S[5120 + node0 * 20 + k40] = *(const float4*)(s0 + 256);
    *(float4*)&S[node1 * 20 + k41] = *(const float4*)s1;
    *(float4*)&S[5120 + node1 * 20 + k41] = *(const float4*)(s1 + 256);
  }
  __syncthreads();
  float acc[2] = {};
#pragma unroll 1
  for (int t = 0; t < 16; ++t) {
    float* buf = S + (t & 1) * 10240;
    float* nbuf = S + ((t + 1) & 1) * 10240;
    float4 gp0, gq0, gp1, gq1;
    const bool more = (t + 1) < 16;
    if (more) {                          // issue next-slice loads early; latency hides under FMAs
      const float* s0 = &pq[(size_t)(gbase + node0) * 512 + (t + 1) * 16 + k40];
      const float* s1 = &pq[(size_t)(gbase + node1) * 512 + (t + 1) * 16 + k41];
      gp0 = *(const float4*)s0; gq0 = *(const float4*)(s0 + 256);
      gp1 = *(const float4*)s1; gq1 = *(const float4*)(s1 + 256);
    }
#pragma unroll
    for (int k4 = 0; k4 < 16; k4 += 4) {
      float4 w4 = *(const float4*)&wm2[t * 16 + k4];
#pragma unroll
      for (int j = 0; j < 2; ++j) {
        float4 p = *(const float4*)&buf[rl[j] + k4];
        float4 q = *(const float4*)&buf[5120 + cl[j] + k4];
        acc[j] = fmaf(w4.x, fmaxf(p.x + q.x, 0.f), acc[j]);
        acc[j] = fmaf(w4.y, fmaxf(p.y + q.y, 0.f), acc[j]);
        acc[j] = fmaf(w4.z, fmaxf(p.z + q.z, 0.f), acc[j]);
        acc[j] = fmaf(w4.w, fmaxf(p.w + q.w, 0.f), acc[j]);
      }
    }
    if (more) {                          // write-late into the other buffer (no WAR with current reads)
      *(float4*)&nbuf[node0 * 20 + k40] = gp0;
      *(float4*)&nbuf[5120 + node0 * 20 + k40] = gq0;
      *(float4*)&nbuf[node1 * 20 + k41] = gp1;
      *(float4*)&nbuf[5120 + node1 * 20 + k41] = gq1;
    }
    __syncthreads();                     // single barrier per t
  }
  const float beta = bm2[0];
#pragma unroll
  for (int j = 0; j < 2; ++j) out[eo[j]] = acc[j] + beta;
#undef PADI
}

// ---------------- bitonic argsort v4 (proven): registers + shfl_xor; LDS only for j>=256 ----------------
__global__ __launch_bounds__(1024) void sort_kernel(float* __restrict__ out, const int* __restrict__ ei,
                                                    int* __restrict__ kg, int* __restrict__ dg,
                                                    int* __restrict__ cmask, int* __restrict__ dmask) {
  __shared__ u64 keys[EPG_];
  const int g = blockIdx.x;
  const int tid = threadIdx.x;
  const int b = 4 * tid;
  u64 e[4];
  {
    float4 s4 = *(const float4*)&out[g * EPG_ + b];
    float sv[4] = {s4.x, s4.y, s4.z, s4.w};
#pragma unroll
    for (int s = 0; s < 4; ++s) {
      unsigned u = __float_as_uint(sv[s]);
      u = (u & 0x80000000u) ? ~u : (u | 0x80000000u);
      e[s] = ((u64)u << 32) | (unsigned)(~(b + s));
    }
  }
  cswap(e[0], e[1], true);
  cswap(e[2], e[3], false);
  {
    bool d = ((b & 4) == 0);
    cswap(e[0], e[2], d); cswap(e[1], e[3], d);
    cswap(e[0], e[1], d); cswap(e[2], e[3], d);
  }
  for (int k = 8; k <= EPG_; k <<= 1) {
    if (k >= 512) {
#pragma unroll
      for (int s = 0; s < 4; ++s) keys[b + s] = e[s];
      __syncthreads();
      for (int j = k >> 1; j >= 256; j >>= 1) {
        const int jm1 = j - 1;
        const int p0 = tid, p1 = tid + 1024;
        const int i0 = ((p0 & ~jm1) << 1) | (p0 & jm1);
        const int i1 = ((p1 & ~jm1) << 1) | (p1 & jm1);
        u64 a0 = keys[i0], b0 = keys[i0 + j];
        u64 a1 = keys[i1], b1 = keys[i1 + j];
        bool d0 = ((i0 & k) == 0), d1 = ((i1 & k) == 0);
        u64 hi0 = a0 > b0 ? a0 : b0, lo0 = a0 > b0 ? b0 : a0;
        u64 hi1 = a1 > b1 ? a1 : b1, lo1 = a1 > b1 ? b1 : a1;
        keys[i0]     = d0 ? hi0 : lo0;
        keys[i0 + j] = d0 ? lo0 : hi0;
        keys[i1]     = d1 ? hi1 : lo1;
        keys[i1 + j] = d1 ? lo1 : hi1;
        __syncthreads();
      }
#pragma unroll
      for (int s = 0; s < 4; ++s) e[s] = keys[b + s];
    }
    const bool d = ((tid & (k >> 2)) == 0);
    for (int j = (k >> 1) > 128 ? 128 : (k >> 1); j >= 4; j >>= 1) {
      const int delta = j >> 2;
      const bool lower = ((tid & delta) == 0);
      const bool keepmax = (lower == d);
#pragma unroll
      for (int s = 0; s < 4; ++s) {
        u64 p = __shfl_xor(e[s], delta);
        u64 mx = e[s] > p ? e[s] : p;
        u64 mn = e[s] > p ? p : e[s];
        e[s] = keepmax ? mx : mn;
      }
    }
    cswap(e[0], e[2], d); cswap(e[1], e[3], d);
    cswap(e[0], e[1], d); cswap(e[2], e[3], d);
  }
#pragma unroll
  for (int s = 0; s < 4; ++s) {
    const int p = b + s;
    u64 kv = e[s];
    int i = (int)(~(unsigned)kv);
    unsigned hi = (unsigned)(kv >> 32);
    unsigned ub = (hi & 0x80000000u) ? (hi ^ 0x80000000u) : ~hi;
    float sc = __uint_as_float(ub);
    int ed = g * EPG_ + i;
    int r = ei[ed], c = ei[EE_ + ed];
    if (p < KK_) {
      out[O_CW + g * KK_ + p] = sc;
      kg[g * KK_ + p] = ed;
      cmask[r] = 1; cmask[c] = 1;
    } else {
      int q = p - KK_;
      out[O_DW + g * KK_ + q] = -sc;
      dg[g * KK_ + q] = ed;
      dmask[r] = 1; dmask[c] = 1;
    }
  }
}

// ---------------- inclusive scan of masks -> nid (cumsum-1); 1 block per mask ----------------
__global__ __launch_bounds__(1024) void scan_kernel(const int* __restrict__ masks, int* __restrict__ nids) {
  const int which = blockIdx.x;
  const int* m = masks + which * NN_;
  int* nid = nids + which * NN_;
  const int tid = threadIdx.x;
  const int base = tid * 32;
  int local[32];
  int sum = 0;
#pragma unroll
  for (int j = 0; j < 32; ++j) { local[j] = m[base + j]; sum += local[j]; }
  __shared__ int ps[1024];
  ps[tid] = sum;
  __syncthreads();
  for (int off = 1; off < 1024; off <<= 1) {
    int v = (tid >= off) ? ps[tid - off] : 0;
    __syncthreads();
    ps[tid] += v;
    __syncthreads();
  }
  int run = ps[tid] - sum;
#pragma unroll
  for (int j = 0; j < 32; ++j) { run += local[j]; nid[base + j] = run - 1; }
}

// ---------------- final gathers ----------------
__global__ __launch_bounds__(256) void finalize_kernel(const int* __restrict__ kg, const int* __restrict__ dg,
                                                       const int* __restrict__ ei,
                                                       const int* __restrict__ nid_c, const int* __restrict__ nid_d,
                                                       const int* __restrict__ cmask, const int* __restrict__ dmask,
                                                       float* __restrict__ out) {
  const int p = blockIdx.x * 256 + threadIdx.x;
  int e = kg[p];
  out[O_CEI + p]       = (float)nid_c[ei[e]];
  out[O_CEI + GK_ + p] = (float)nid_c[ei[EE_ + e]];
  int e2 = dg[p];
  out[O_FEI + p]       = (float)nid_d[ei[e2]];
  out[O_FEI + GK_ + p] = (float)nid_d[ei[EE_ + e2]];
  if (p < NN_) {
    out[O_CM + p] = (float)cmask[p];
    out[O_DM + p] = (float)dmask[p];
  }
}

extern "C" void kernel_launch(void* const* d_in, const int* in_sizes, int n_in,
                              void* d_out, int out_size, void* d_ws, size_t ws_size,
                              hipStream_t stream) {
  (void)in_sizes; (void)n_in; (void)out_size; (void)ws_size;
  const float* x   = (const float*)d_in[0];
  const float* ea  = (const float*)d_in[1];
  const float* W11 = (const float*)d_in[2];
  const float* b11 = (const float*)d_in[3];
  const float* W12 = (const float*)d_in[4];
  const float* W13 = (const float*)d_in[5];
  const float* b13 = (const float*)d_in[6];
  const float* W21 = (const float*)d_in[7];
  const float* b21 = (const float*)d_in[8];
  const float* W22 = (const float*)d_in[9];
  const float* W23 = (const float*)d_in[10];
  const float* b23 = (const float*)d_in[11];
  const float* Wm1 = (const float*)d_in[12];
  const float* bm1 = (const float*)d_in[13];
  const float* Wm2 = (const float*)d_in[14];
  const float* bm2 = (const float*)d_in[15];
  const int*   ei  = (const int*)d_in[16];
  float* out = (float*)d_out;
  float* ws  = (float*)d_ws;

  // workspace (float offsets), phase-overlapped (unchanged 78.1 MB footprint):
  //   MT  [0, 8388608)          32 MB   (dead after mm_agg #2; fully written by build_dense — no memset)
  //   Wc  [8388608, 8421376)    128 KB  (fully written by build_dense)
  //   buf [8421376, 14712832)   24 MB   (dead after mm_agg #2)
  //   pq  [0, 16777216)         64 MB   overlaps MT/Wc/buf, written after all dead
  //   h_c [16777216, 18874368)  8 MB
  //   ints from 18874368: kg GK, dg GK, cmask N, dmask N, nid_c N, nid_d N
  //   WT aliases kg: WmT 32768 + W1T 12288 + W2T 12288 = 57344 floats < GK.
  float* MT  = ws;
  float* Wc  = ws + 8388608;
  float* buf = ws + 8421376;
  float* pq  = ws;
  float* h_c = ws + 16777216;
  int* kg    = (int*)(ws + 18874368);
  int* dg    = kg + GK_;
  int* cmask = dg + GK_;
  int* dmask = cmask + NN_;
  int* nid_c = dmask + NN_;
  int* nid_d = nid_c + NN_;
  float* WmT = ws + 18874368;            // aliases kg
  float* W1T = WmT + 32768;
  float* W2T = W1T + 12288;

  prep_kernel<<<160, 256, 0, stream>>>(Wm1, W11, W12, W13, W21, W22, W23, WmT, W1T, W2T, cmask);

  build_dense<<<256, 256, 0, stream>>>(ei, ea, MT, Wc);

  BiasCfg bc1{};
  bc1.b[0] = b11; bc1.b[1] = nullptr; bc1.b[2] = b13;
  gemm_wt<<<dim3(512, 3), 256, 0, stream>>>(x, 64, W1T, 192, bc1, 1, buf, 192);

  mm_agg2<<<256, 256, 0, stream>>>(MT, buf, Wc, h_c, /*relu=*/1);

  BiasCfg bc2{};
  bc2.b[0] = b21; bc2.b[1] = nullptr; bc2.b[2] = b23;
  gemm_wt<<<dim3(512, 3), 256, 0, stream>>>(h_c, 64, W2T, 192, bc2, 1, buf, 192);

  mm_agg2<<<256, 256, 0, stream>>>(MT, buf, Wc, h_c, /*relu=*/0);

  BiasCfg bc3{};
  for (int cb = 0; cb < 4; ++cb) { bc3.b[cb] = bm1 + cb * 64; bc3.b[cb + 4] = nullptr; }
  gemm_wt8<<<dim3(256, 2), 256, 0, stream>>>(h_c, 64, WmT, 512, bc3, 4, pq, 512);

  score_v16<<<512, 512, 0, stream>>>(pq, ei, Wm2, bm2, out);

  sort_kernel<<<G_, 1024, 0, stream>>>(out, ei, kg, dg, cmask, dmask);

  scan_kernel<<<2, 1024, 0, stream>>>(cmask, nid_c);

  finalize_kernel<<<GK_ / 256, 256, 0, stream>>>(kg, dg, ei, nid_c, nid_d, cmask, dmask, out);
}

// Round 17
// 305.119 us; speedup vs baseline: 1.0422x; 1.0422x over previous
//
#include <hip/hip_runtime.h>
#include <cstddef>

#define G_    128
#define NPG_  256
#define EPG_  4096
#define NN_   32768
#define EE_   524288
#define KK_   2048
#define GK_   262144

// d_out layout (floats): [score E][causal_w GK][conf_w GK][causal_ei 2*GK][conf_ei 2*GK][cmask N][dmask N]
#define O_CW  524288
#define O_DW  786432
#define O_CEI 1048576
#define O_FEI 1572864
#define O_CM  2097152
#define O_DM  2129920

typedef float v4f __attribute__((ext_vector_type(4)));
typedef unsigned long long u64;

struct BiasCfg {
  const float* b[8];
};

__device__ __forceinline__ void cswap(u64& a, u64& b, bool d) {
  u64 hi = a > b ? a : b, lo = a > b ? b : a;
  a = d ? hi : lo;
  b = d ? lo : hi;
}

// ---------------- GEMM body (gemm#1/#2): GLOBAL-W 4x4, nt stores, N-split (proven best:
// R9-ledger showed W-in-LDS at ncb=1 has zero amortization, +10us/launch). nt-envelope rule:
// <=1 outstanding nt stream per block — __syncthreads() AFTER each cb's store burst. ----------------
__device__ __forceinline__ void gemm_wt_body(const float* __restrict__ in, int istride,
                                             const float* __restrict__ WT, int wstride,
                                             const BiasCfg& bc, int cb0, int ncb,
                                             float* __restrict__ out, int ostride,
                                             int bx, float* xT) {
  const int tid = threadIdx.x;
  const int r0 = bx * 64;
#pragma unroll
  for (int it = 0; it < 16; ++it) {
    int idx = tid + it * 256;
    int rr = idx >> 6, kk = idx & 63;
    xT[kk * 68 + rr] = in[(r0 + rr) * istride + kk];
  }
  __syncthreads();
  const int c4 = (tid & 15) * 4;
  const int r4 = (tid >> 4) * 4;
  for (int cb = cb0; cb < cb0 + ncb; ++cb) {
    const float* wp = WT + cb * 64 + c4;
    const float* bp = bc.b[cb];
    float acc[4][4] = {};
#pragma unroll
    for (int k = 0; k < 64; ++k) {
      float4 xv = *(const float4*)&xT[k * 68 + r4];
      float4 wv = *(const float4*)&wp[(size_t)k * wstride];
      float xr[4] = {xv.x, xv.y, xv.z, xv.w};
      float wc[4] = {wv.x, wv.y, wv.z, wv.w};
#pragma unroll
      for (int a = 0; a < 4; ++a)
#pragma unroll
        for (int b = 0; b < 4; ++b)
          acc[a][b] = fmaf(xr[a], wc[b], acc[a][b]);
    }
    float bx4[4] = {0.f, 0.f, 0.f, 0.f};
    if (bp) {
      float4 bb = *(const float4*)&bp[c4];
      bx4[0] = bb.x; bx4[1] = bb.y; bx4[2] = bb.z; bx4[3] = bb.w;
    }
#pragma unroll
    for (int ri = 0; ri < 4; ++ri) {
      v4f st;
      st.x = acc[ri][0] + bx4[0];
      st.y = acc[ri][1] + bx4[1];
      st.z = acc[ri][2] + bx4[2];
      st.w = acc[ri][3] + bx4[3];
      __builtin_nontemporal_store(st, (v4f*)&out[(r0 + r4 + ri) * ostride + cb * 64 + c4]);
    }
    __syncthreads();  // drain nt burst — the nt-envelope invariant
  }
}

__global__ __launch_bounds__(256, 4) void gemm_wt(const float* __restrict__ in, int istride,
                                                  const float* __restrict__ WT, int wstride,
                                                  BiasCfg bc, int ncb_per,
                                                  float* __restrict__ out, int ostride) {
  __shared__ float xT[64 * 68];
  gemm_wt_body(in, istride, WT, wstride, bc, blockIdx.y * ncb_per, ncb_per,
               out, ostride, blockIdx.x, xT);
}

// ---------------- gemm_wt8 (proven, for gemm#3): 128x128 (cb pair) tile, 8x8/thread,
// W staged in LDS, nt stores. Probed 5 ways (occupancy/reg-pipeline/W-source/blocking/
// store-path) — all null; closed at ~42us (latency-bound at 2 waves/SIMD, 68.6KB LDS). ----------------
__global__ __launch_bounds__(256, 2) void gemm_wt8(const float* __restrict__ in, int istride,
                                                   const float* __restrict__ WT, int wstride,
                                                   BiasCfg bc, int cbs_per_y,
                                                   float* __restrict__ out, int ostride) {
  __shared__ float xT[64 * 132];   // [k][row 0..127], pad 4
  __shared__ float wS[64 * 136];   // [k][pair: cb0 cols @0, cb1 cols @68]
  const int tid = threadIdx.x;
  const int r0 = blockIdx.x * 128;
  const int cbbase = blockIdx.y * cbs_per_y;
#pragma unroll
  for (int it = 0; it < 32; ++it) {
    int idx = tid + it * 256;            // 0..8191: 128 rows x 64 k
    int rr = idx >> 6, kk = idx & 63;
    xT[kk * 132 + rr] = in[(size_t)(r0 + rr) * istride + kk];
  }
  const int c4 = (tid & 15) * 4;
  const int r8 = (tid >> 4) * 8;
  for (int pr = 0; pr < cbs_per_y; pr += 2) {
    const int cb0 = cbbase + pr;
#pragma unroll
    for (int it = 0; it < 8; ++it) {     // stage both panels of the pair
      int idx = tid + it * 256;          // 0..2047 float4 slots
      int p = idx >> 10, rem = idx & 1023;
      int k = rem >> 4, c16 = (rem & 15) * 4;
      *(float4*)&wS[k * 136 + p * 68 + c16] =
          *(const float4*)&WT[(size_t)k * wstride + (cb0 + p) * 64 + c16];
    }
    __syncthreads();                     // wS (and on first pair: xT) ready
    float acc0[8][4] = {};
    float acc1[8][4] = {};
#pragma unroll 4
    for (int k = 0; k < 64; ++k) {
      float4 xlo = *(const float4*)&xT[k * 132 + r8];
      float4 xhi = *(const float4*)&xT[k * 132 + r8 + 4];
      float4 w0 = *(const float4*)&wS[k * 136 + c4];
      float4 w1 = *(const float4*)&wS[k * 136 + 68 + c4];
      float xr[8] = {xlo.x, xlo.y, xlo.z, xlo.w, xhi.x, xhi.y, xhi.z, xhi.w};
      float wc0[4] = {w0.x, w0.y, w0.z, w0.w};
      float wc1[4] = {w1.x, w1.y, w1.z, w1.w};
#pragma unroll
      for (int a = 0; a < 8; ++a) {
#pragma unroll
        for (int b = 0; b < 4; ++b) {
          acc0[a][b] = fmaf(xr[a], wc0[b], acc0[a][b]);
          acc1[a][b] = fmaf(xr[a], wc1[b], acc1[a][b]);
        }
      }
    }
    {
      const float* bp = bc.b[cb0];
      float b4[4] = {0.f, 0.f, 0.f, 0.f};
      if (bp) {
        float4 bb = *(const float4*)&bp[c4];
        b4[0] = bb.x; b4[1] = bb.y; b4[2] = bb.z; b4[3] = bb.w;
      }
#pragma unroll
      for (int ri = 0; ri < 8; ++ri) {
        v4f st;
        st.x = acc0[ri][0] + b4[0];
        st.y = acc0[ri][1] + b4[1];
        st.z = acc0[ri][2] + b4[2];
        st.w = acc0[ri][3] + b4[3];
        __builtin_nontemporal_store(st, (v4f*)&out[(size_t)(r0 + r8 + ri) * ostride + cb0 * 64 + c4]);
      }
      __syncthreads();                   // drain cb0 nt burst
    }
    {
      const float* bp = bc.b[cb0 + 1];
      float b4[4] = {0.f, 0.f, 0.f, 0.f};
      if (bp) {
        float4 bb = *(const float4*)&bp[c4];
        b4[0] = bb.x; b4[1] = bb.y; b4[2] = bb.z; b4[3] = bb.w;
      }
#pragma unroll
      for (int ri = 0; ri < 8; ++ri) {
        v4f st;
        st.x = acc1[ri][0] + b4[0];
        st.y = acc1[ri][1] + b4[1];
        st.z = acc1[ri][2] + b4[2];
        st.w = acc1[ri][3] + b4[3];
        __builtin_nontemporal_store(st, (v4f*)&out[(size_t)(r0 + r8 + ri) * ostride + (cb0 + 1) * 64 + c4]);
      }
      __syncthreads();                   // drain cb1 nt burst; guards wS restage
    }
  }
}

// ---------------- prep: weight transposes (WmT/W1T/W2T) + zero masks ----------------
__global__ __launch_bounds__(256) void prep_kernel(const float* __restrict__ Wm1,
                                                   const float* __restrict__ W11, const float* __restrict__ W12,
                                                   const float* __restrict__ W13,
                                                   const float* __restrict__ W21, const float* __restrict__ W22,
                                                   const float* __restrict__ W23,
                                                   float* __restrict__ WmT, float* __restrict__ W1T,
                                                   float* __restrict__ W2T, int* __restrict__ masks) {
  const int b = blockIdx.x;
  const int tid = threadIdx.x;
  if (b < 64) {
    const int k = b;
#pragma unroll
    for (int t = 0; t < 2; ++t) {
      int j = t * 256 + tid;
      int row = j & 255;
      int koff = (j < 256) ? 0 : 64;
      WmT[k * 512 + j] = Wm1[row * 128 + koff + k];
    }
  } else if (b < 80) {
    const int kb = (b - 64) * 4;
    if (tid < 192) {
      int cb = tid >> 6, c = tid & 63;
      const float* Wsrc = (cb == 0) ? W11 : (cb == 1) ? W12 : W13;
#pragma unroll
      for (int s = 0; s < 4; ++s) {
        int k = kb + s;
        W1T[k * 192 + tid] = Wsrc[c * 64 + k];
      }
    }
  } else if (b < 96) {
    const int kb = (b - 80) * 4;
    if (tid < 192) {
      int cb = tid >> 6, c = tid & 63;
      const float* Wsrc = (cb == 0) ? W21 : (cb == 1) ? W22 : W23;
#pragma unroll
      for (int s = 0; s < 4; ++s) {
        int k = kb + s;
        W2T[k * 192 + tid] = Wsrc[c * 64 + k];
      }
    }
  } else {
    int idx = (b - 96) * 1024 + tid * 4;  // 64 blocks x 1024 ints = 65536 = 2*NN
    int4 z = {0, 0, 0, 0};
    *(int4*)&masks[idx] = z;
  }
}

// ---------------- build_dense: per-(group, col-half) LDS accumulation — no global atomics,
// no MT memset (every cell written), Wc = LDS column sums (no contention) ----------------
__global__ __launch_bounds__(256) void build_dense(const int* __restrict__ ei, const float* __restrict__ ea,
                                                   float* __restrict__ MT, float* __restrict__ Wc) {
  __shared__ float acc[NPG_ * 128];  // 128 KB: 256 rows x 128 cols (this block's column half)
  const int tid = threadIdx.x;
  const int g = blockIdx.x >> 1;
  const int c0 = (blockIdx.x & 1) * 128;
  const int gbase = g * NPG_;
  const size_t mbase = (size_t)g << 16;
  for (int i = tid * 4; i < NPG_ * 128; i += 1024) {
    float4 z = {0.f, 0.f, 0.f, 0.f};
    *(float4*)&acc[i] = z;
  }
  __syncthreads();
  const int ebase = g * EPG_;
#pragma unroll
  for (int it = 0; it < 16; ++it) {
    int e = ebase + it * 256 + tid;
    int r = ei[e] - gbase;
    int ch = ei[EE_ + e] - gbase - c0;
    float w = ea[e];
    if ((unsigned)ch < 128u) atomicAdd(&acc[r * 128 + ch], w);
  }
  __syncthreads();
  // write the half-slab: each row contributes 512 B aligned chunk
  for (int i = tid; i < NPG_ * 32; i += 256) {
    int r = i >> 5, c4 = (i & 31) * 4;
    *(float4*)&MT[mbase + (size_t)r * 256 + c0 + c4] = *(const float4*)&acc[r * 128 + c4];
  }
  // Wc column sums (lanes own columns; per-lane serial over r)
  if (tid < 128) {
    float s = 0.f;
    for (int r = 0; r < NPG_; ++r) s += acc[r * 128 + tid];
    Wc[gbase + c0 + tid] = s;
  }
}

// ---------------- dense leconv aggregation (4x4, proven R15-best): h[c] = sum_r MT[r][c]*A[r]
// - Wc[c]*B[c] + C[c]. v20's 8x4 widening (3 blocks/CU) regressed/was-noise (318 vs 306) —
// reverted per pre-commitment; 16 waves/CU latency-hiding beats fewer LDS reads here. ----------------
__global__ __launch_bounds__(256) void mm_agg(const float* __restrict__ MT, const float* __restrict__ buf,
                                              const float* __restrict__ Wc, float* __restrict__ hout,
                                              int do_relu) {
  __shared__ float Ms[64 * 72];
  __shared__ float As[64 * 72];
  const int tid = threadIdx.x;
  const int g = blockIdx.x >> 2;
  const int c0 = (blockIdx.x & 3) * 64;
  const int gbase = g * NPG_;
  const size_t mbase = (size_t)g << 16;
  const int c4 = (tid >> 4) * 4;   // output node within tile
  const int k4 = (tid & 15) * 4;   // feature (lane-contiguous)
  float acc[4][4] = {};
  for (int kc = 0; kc < 4; ++kc) {
#pragma unroll
    for (int it = 0; it < 4; ++it) {
      int idx = tid + it * 256;       // 0..1023
      int rr = idx >> 4, c16 = (idx & 15) * 4;
      *(float4*)&Ms[rr * 72 + c16] = *(const float4*)&MT[mbase + (size_t)(kc * 64 + rr) * 256 + c0 + c16];
      *(float4*)&As[rr * 72 + c16] = *(const float4*)&buf[(gbase + kc * 64 + rr) * 192 + c16];
    }
    __syncthreads();
#pragma unroll
    for (int r = 0; r < 64; ++r) {
      float4 mv = *(const float4*)&Ms[r * 72 + c4];
      float4 av = *(const float4*)&As[r * 72 + k4];
      float mr[4] = {mv.x, mv.y, mv.z, mv.w};
      float ak[4] = {av.x, av.y, av.z, av.w};
#pragma unroll
      for (int ci = 0; ci < 4; ++ci)
#pragma unroll
        for (int ki = 0; ki < 4; ++ki)
          acc[ci][ki] = fmaf(mr[ci], ak[ki], acc[ci][ki]);
    }
    __syncthreads();
  }
#pragma unroll
  for (int ci = 0; ci < 4; ++ci) {
    int n = gbase + c0 + c4 + ci;
    float wcn = Wc[n];
    float4 b4 = *(const float4*)&buf[n * 192 + 64 + k4];
    float4 cc4 = *(const float4*)&buf[n * 192 + 128 + k4];
    float4 st;
    st.x = acc[ci][0] - wcn * b4.x + cc4.x;
    st.y = acc[ci][1] - wcn * b4.y + cc4.y;
    st.z = acc[ci][2] - wcn * b4.z + cc4.z;
    st.w = acc[ci][3] - wcn * b4.w + cc4.w;
    if (do_relu) {
      st.x = fmaxf(st.x, 0.f); st.y = fmaxf(st.y, 0.f);
      st.z = fmaxf(st.z, 0.f); st.w = fmaxf(st.w, 0.f);
    }
    *(float4*)&hout[n * 64 + k4] = st;
  }
}

// ---------------- fused edge scores v16 (proven): v12 machinery + double-buffered t-slices,
// one barrier per t, T14 issue-early/write-late staging. Per-edge fp chain (t asc, k4 asc)
// matches v5..v12 -> scores bitwise-identical. ----------------
__global__ __launch_bounds__(512, 2) void score_v16(const float* __restrict__ pq, const int* __restrict__ ei,
                                                    const float* __restrict__ wm2, const float* __restrict__ bm2,
                                                    float* __restrict__ out) {
  __shared__ __align__(16) float S[20480];   // 80KB: buf0=[0,10240) buf1=[10240,20480); each = Ps[5120]+Qs[5120]
  int* ip = (int*)S;
  const int tid = threadIdx.x;
  const int g = blockIdx.x & 127;       // same-g blocks ≡ g (mod 8) -> same XCD, pq L2 reuse
  const int quarter = blockIdx.x >> 7;
  const int gbase = g * NPG_;
  const int ebase = g * EPG_ + quarter * 1024;
  // pad slot i (i in [0,2048)) -> float index (i>>2)*20 + 16 + (i&3)  (buffer-0 row pads)
  // slots: sorted[0,1024) hist[1024,1280) off[1280,1536) cur[1536,1792) wsum[1792,1796)
#define PADI(i) ((((i) >> 2) * 20) + 16 + ((i) & 3))
  if (tid < 256) { ip[PADI(1024 + tid)] = 0; ip[PADI(1536 + tid)] = 0; }
  int rr[2], cc[2];
#pragma unroll
  for (int j = 0; j < 2; ++j) {
    int e = ebase + j * 512 + tid;
    rr[j] = ei[e] - gbase;
    cc[j] = ei[EE_ + e] - gbase;
  }
  __syncthreads();
#pragma unroll
  for (int j = 0; j < 2; ++j) atomicAdd(&ip[PADI(1024 + rr[j])], 1);
  __syncthreads();
  int sv = 0, vv = 0;
  if (tid < 256) {                      // waves 0-3: 4x 64-lane inclusive scans
    const int l = tid & 63;
    vv = ip[PADI(1024 + tid)];
    sv = vv;
#pragma unroll
    for (int d = 1; d < 64; d <<= 1) {
      int u = __shfl_up(sv, d);
      if (l >= d) sv += u;
    }
    if (l == 63) ip[PADI(1792 + (tid >> 6))] = sv;
  }
  __syncthreads();
  if (tid < 256) {
    const int w = tid >> 6;
    int woff = 0;
#pragma unroll
    for (int ww = 0; ww < 3; ++ww)
      if (ww < w) woff += ip[PADI(1792 + ww)];
    ip[PADI(1280 + tid)] = woff + sv - vv;  // block-wide exclusive prefix (bucket start)
  }
  __syncthreads();
#pragma unroll
  for (int j = 0; j < 2; ++j) {
    int pos = ip[PADI(1280 + rr[j])] + atomicAdd(&ip[PADI(1536 + rr[j])], 1);
    ip[PADI(pos)] = (rr[j] << 19) | (cc[j] << 11) | (j * 512 + tid);
  }
  __syncthreads();
  int rl[2], cl[2], eo[2];
#pragma unroll
  for (int j = 0; j < 2; ++j) {          // consecutive lanes <- consecutive sorted ranks
    int rec = ip[PADI(j * 512 + tid)];
    rl[j] = (rec >> 19) * 20;
    cl[j] = ((rec >> 11) & 255) * 20;
    eo[j] = ebase + (rec & 2047);
  }
  // stage t=0 into buffer 0 (data lanes only; pads with sort records untouched, and the
  // records are already consumed into registers above)
  const int node0 = tid >> 2, k40 = (tid & 3) * 4;
  const int node1 = 128 + node0, k41 = k40;
  {
    const float* s0 = &pq[(size_t)(gbase + node0) * 512 + k40];
    const float* s1 = &pq[(size_t)(gbase + node1) * 512 + k41];
    *(float4*)&S[node0 * 20 + k40] = *(const float4*)s0;
    *(float4*)&S[5120 + node0 * 20 + k40] = *(const float4*)(s0 + 256);
    *(float4*)&S[node1 * 20 + k41] = *(const float4*)s1;
    *(float4*)&S[5120 + node1 * 20 + k41] = *(const float4*)(s1 + 256);
  }
  __syncthreads();
  float acc[2] = {};
#pragma unroll 1
  for (int t = 0; t < 16; ++t) {
    float* buf = S + (t & 1) * 10240;
    float* nbuf = S + ((t + 1) & 1) * 10240;
    float4 gp0, gq0, gp1, gq1;
    const bool more = (t + 1) < 16;
    if (more) {                          // issue next-slice loads early; latency hides under FMAs
      const float* s0 = &pq[(size_t)(gbase + node0) * 512 + (t + 1) * 16 + k40];
      const float* s1 = &pq[(size_t)(gbase + node1) * 512 + (t + 1) * 16 + k41];
      gp0 = *(const float4*)s0; gq0 = *(const float4*)(s0 + 256);
      gp1 = *(const float4*)s1; gq1 = *(const float4*)(s1 + 256);
    }
#pragma unroll
    for (int k4 = 0; k4 < 16; k4 += 4) {
      float4 w4 = *(const float4*)&wm2[t * 16 + k4];
#pragma unroll
      for (int j = 0; j < 2; ++j) {
        float4 p = *(const float4*)&buf[rl[j] + k4];
        float4 q = *(const float4*)&buf[5120 + cl[j] + k4];
        acc[j] = fmaf(w4.x, fmaxf(p.x + q.x, 0.f), acc[j]);
        acc[j] = fmaf(w4.y, fmaxf(p.y + q.y, 0.f), acc[j]);
        acc[j] = fmaf(w4.z, fmaxf(p.z + q.z, 0.f), acc[j]);
        acc[j] = fmaf(w4.w, fmaxf(p.w + q.w, 0.f), acc[j]);
      }
    }
    if (more) {                          // write-late into the other buffer (no WAR with current reads)
      *(float4*)&nbuf[node0 * 20 + k40] = gp0;
      *(float4*)&nbuf[5120 + node0 * 20 + k40] = gq0;
      *(float4*)&nbuf[node1 * 20 + k41] = gp1;
      *(float4*)&nbuf[5120 + node1 * 20 + k41] = gq1;
    }
    __syncthreads();                     // single barrier per t
  }
  const float beta = bm2[0];
#pragma unroll
  for (int j = 0; j < 2; ++j) out[eo[j]] = acc[j] + beta;
#undef PADI
}

// ---------------- bitonic argsort v4 (proven): registers + shfl_xor; LDS only for j>=256 ----------------
__global__ __launch_bounds__(1024) void sort_kernel(float* __restrict__ out, const int* __restrict__ ei,
                                                    int* __restrict__ kg, int* __restrict__ dg,
                                                    int* __restrict__ cmask, int* __restrict__ dmask) {
  __shared__ u64 keys[EPG_];
  const int g = blockIdx.x;
  const int tid = threadIdx.x;
  const int b = 4 * tid;
  u64 e[4];
  {
    float4 s4 = *(const float4*)&out[g * EPG_ + b];
    float sv[4] = {s4.x, s4.y, s4.z, s4.w};
#pragma unroll
    for (int s = 0; s < 4; ++s) {
      unsigned u = __float_as_uint(sv[s]);
      u = (u & 0x80000000u) ? ~u : (u | 0x80000000u);
      e[s] = ((u64)u << 32) | (unsigned)(~(b + s));
    }
  }
  cswap(e[0], e[1], true);
  cswap(e[2], e[3], false);
  {
    bool d = ((b & 4) == 0);
    cswap(e[0], e[2], d); cswap(e[1], e[3], d);
    cswap(e[0], e[1], d); cswap(e[2], e[3], d);
  }
  for (int k = 8; k <= EPG_; k <<= 1) {
    if (k >= 512) {
#pragma unroll
      for (int s = 0; s < 4; ++s) keys[b + s] = e[s];
      __syncthreads();
      for (int j = k >> 1; j >= 256; j >>= 1) {
        const int jm1 = j - 1;
        const int p0 = tid, p1 = tid + 1024;
        const int i0 = ((p0 & ~jm1) << 1) | (p0 & jm1);
        const int i1 = ((p1 & ~jm1) << 1) | (p1 & jm1);
        u64 a0 = keys[i0], b0 = keys[i0 + j];
        u64 a1 = keys[i1], b1 = keys[i1 + j];
        bool d0 = ((i0 & k) == 0), d1 = ((i1 & k) == 0);
        u64 hi0 = a0 > b0 ? a0 : b0, lo0 = a0 > b0 ? b0 : a0;
        u64 hi1 = a1 > b1 ? a1 : b1, lo1 = a1 > b1 ? b1 : a1;
        keys[i0]     = d0 ? hi0 : lo0;
        keys[i0 + j] = d0 ? lo0 : hi0;
        keys[i1]     = d1 ? hi1 : lo1;
        keys[i1 + j] = d1 ? lo1 : hi1;
        __syncthreads();
      }
#pragma unroll
      for (int s = 0; s < 4; ++s) e[s] = keys[b + s];
    }
    const bool d = ((tid & (k >> 2)) == 0);
    for (int j = (k >> 1) > 128 ? 128 : (k >> 1); j >= 4; j >>= 1) {
      const int delta = j >> 2;
      const bool lower = ((tid & delta) == 0);
      const bool keepmax = (lower == d);
#pragma unroll
      for (int s = 0; s < 4; ++s) {
        u64 p = __shfl_xor(e[s], delta);
        u64 mx = e[s] > p ? e[s] : p;
        u64 mn = e[s] > p ? p : e[s];
        e[s] = keepmax ? mx : mn;
      }
    }
    cswap(e[0], e[2], d); cswap(e[1], e[3], d);
    cswap(e[0], e[1], d); cswap(e[2], e[3], d);
  }
#pragma unroll
  for (int s = 0; s < 4; ++s) {
    const int p = b + s;
    u64 kv = e[s];
    int i = (int)(~(unsigned)kv);
    unsigned hi = (unsigned)(kv >> 32);
    unsigned ub = (hi & 0x80000000u) ? (hi ^ 0x80000000u) : ~hi;
    float sc = __uint_as_float(ub);
    int ed = g * EPG_ + i;
    int r = ei[ed], c = ei[EE_ + ed];
    if (p < KK_) {
      out[O_CW + g * KK_ + p] = sc;
      kg[g * KK_ + p] = ed;
      cmask[r] = 1; cmask[c] = 1;
    } else {
      int q = p - KK_;
      out[O_DW + g * KK_ + q] = -sc;
      dg[g * KK_ + q] = ed;
      dmask[r] = 1; dmask[c] = 1;
    }
  }
}

// ---------------- inclusive scan of masks -> nid (cumsum-1); 1 block per mask ----------------
__global__ __launch_bounds__(1024) void scan_kernel(const int* __restrict__ masks, int* __restrict__ nids) {
  const int which = blockIdx.x;
  const int* m = masks + which * NN_;
  int* nid = nids + which * NN_;
  const int tid = threadIdx.x;
  const int base = tid * 32;
  int local[32];
  int sum = 0;
#pragma unroll
  for (int j = 0; j < 32; ++j) { local[j] = m[base + j]; sum += local[j]; }
  __shared__ int ps[1024];
  ps[tid] = sum;
  __syncthreads();
  for (int off = 1; off < 1024; off <<= 1) {
    int v = (tid >= off) ? ps[tid - off] : 0;
    __syncthreads();
    ps[tid] += v;
    __syncthreads();
  }
  int run = ps[tid] - sum;
#pragma unroll
  for (int j = 0; j < 32; ++j) { run += local[j]; nid[base + j] = run - 1; }
}

// ---------------- final gathers ----------------
__global__ __launch_bounds__(256) void finalize_kernel(const int* __restrict__ kg, const int* __restrict__ dg,
                                                       const int* __restrict__ ei,
                                                       const int* __restrict__ nid_c, const int* __restrict__ nid_d,
                                                       const int* __restrict__ cmask, const int* __restrict__ dmask,
                                                       float* __restrict__ out) {
  const int p = blockIdx.x * 256 + threadIdx.x;
  int e = kg[p];
  out[O_CEI + p]       = (float)nid_c[ei[e]];
  out[O_CEI + GK_ + p] = (float)nid_c[ei[EE_ + e]];
  int e2 = dg[p];
  out[O_FEI + p]       = (float)nid_d[ei[e2]];
  out[O_FEI + GK_ + p] = (float)nid_d[ei[EE_ + e2]];
  if (p < NN_) {
    out[O_CM + p] = (float)cmask[p];
    out[O_DM + p] = (float)dmask[p];
  }
}

extern "C" void kernel_launch(void* const* d_in, const int* in_sizes, int n_in,
                              void* d_out, int out_size, void* d_ws, size_t ws_size,
                              hipStream_t stream) {
  (void)in_sizes; (void)n_in; (void)out_size; (void)ws_size;
  const float* x   = (const float*)d_in[0];
  const float* ea  = (const float*)d_in[1];
  const float* W11 = (const float*)d_in[2];
  const float* b11 = (const float*)d_in[3];
  const float* W12 = (const float*)d_in[4];
  const float* W13 = (const float*)d_in[5];
  const float* b13 = (const float*)d_in[6];
  const float* W21 = (const float*)d_in[7];
  const float* b21 = (const float*)d_in[8];
  const float* W22 = (const float*)d_in[9];
  const float* W23 = (const float*)d_in[10];
  const float* b23 = (const float*)d_in[11];
  const float* Wm1 = (const float*)d_in[12];
  const float* bm1 = (const float*)d_in[13];
  const float* Wm2 = (const float*)d_in[14];
  const float* bm2 = (const float*)d_in[15];
  const int*   ei  = (const int*)d_in[16];
  float* out = (float*)d_out;
  float* ws  = (float*)d_ws;

  // workspace (float offsets), phase-overlapped (unchanged 78.1 MB footprint):
  //   MT  [0, 8388608)          32 MB   (dead after mm_agg #2; fully written by build_dense — no memset)
  //   Wc  [8388608, 8421376)    128 KB  (fully written by build_dense)
  //   buf [8421376, 14712832)   24 MB   (dead after mm_agg #2)
  //   pq  [0, 16777216)         64 MB   overlaps MT/Wc/buf, written after all dead
  //   h_c [16777216, 18874368)  8 MB
  //   ints from 18874368: kg GK, dg GK, cmask N, dmask N, nid_c N, nid_d N
  //   WT aliases kg: WmT 32768 + W1T 12288 + W2T 12288 = 57344 floats < GK.
  float* MT  = ws;
  float* Wc  = ws + 8388608;
  float* buf = ws + 8421376;
  float* pq  = ws;
  float* h_c = ws + 16777216;
  int* kg    = (int*)(ws + 18874368);
  int* dg    = kg + GK_;
  int* cmask = dg + GK_;
  int* dmask = cmask + NN_;
  int* nid_c = dmask + NN_;
  int* nid_d = nid_c + NN_;
  float* WmT = ws + 18874368;            // aliases kg
  float* W1T = WmT + 32768;
  float* W2T = W1T + 12288;

  prep_kernel<<<160, 256, 0, stream>>>(Wm1, W11, W12, W13, W21, W22, W23, WmT, W1T, W2T, cmask);

  build_dense<<<256, 256, 0, stream>>>(ei, ea, MT, Wc);

  BiasCfg bc1{};
  bc1.b[0] = b11; bc1.b[1] = nullptr; bc1.b[2] = b13;
  gemm_wt<<<dim3(512, 3), 256, 0, stream>>>(x, 64, W1T, 192, bc1, 1, buf, 192);

  mm_agg<<<512, 256, 0, stream>>>(MT, buf, Wc, h_c, /*relu=*/1);

  BiasCfg bc2{};
  bc2.b[0] = b21; bc2.b[1] = nullptr; bc2.b[2] = b23;
  gemm_wt<<<dim3(512, 3), 256, 0, stream>>>(h_c, 64, W2T, 192, bc2, 1, buf, 192);

  mm_agg<<<512, 256, 0, stream>>>(MT, buf, Wc, h_c, /*relu=*/0);

  BiasCfg bc3{};
  for (int cb = 0; cb < 4; ++cb) { bc3.b[cb] = bm1 + cb * 64; bc3.b[cb + 4] = nullptr; }
  gemm_wt8<<<dim3(256, 2), 256, 0, stream>>>(h_c, 64, WmT, 512, bc3, 4, pq, 512);

  score_v16<<<512, 512, 0, stream>>>(pq, ei, Wm2, bm2, out);

  sort_kernel<<<G_, 1024, 0, stream>>>(out, ei, kg, dg, cmask, dmask);

  scan_kernel<<<2, 1024, 0, stream>>>(cmask, nid_c);

  finalize_kernel<<<GK_ / 256, 256, 0, stream>>>(kg, dg, ei, nid_c, nid_d, cmask, dmask, out);
}